// Round 17
// baseline (256.049 us; speedup 1.0000x reference)
//
#include <hip/hip_runtime.h>
#include <stdint.h>

typedef unsigned short u16;

#define Bb 4
#define Hh 4
#define Tt 8
#define Cc 256
#define NP 196
#define Ss 1568                 // Tt*NP
#define SCALE_S 0.0252538136f   // 1/sqrt(1568)
#define LST 32                  // LDS row stride (elems); 40 measured worse (R15)

typedef __attribute__((ext_vector_type(4))) float floatx4;
typedef __attribute__((ext_vector_type(8))) short shortx8;
typedef __attribute__((ext_vector_type(4))) short shortx4;

__device__ __forceinline__ float bf2f(u16 u) {
    union { unsigned u; float f; } v; v.u = ((unsigned)u) << 16; return v.f;
}
__device__ __forceinline__ u16 f2bf(float f) {
    union { float f; unsigned u; } v; v.f = f;
    unsigned r = v.u + 0x7FFFu + ((v.u >> 16) & 1u);
    return (u16)(r >> 16);
}

// ---- K0: all weights fp32 -> one bf16 buffer [Wq|Wk|Wv|Wo] ----
__global__ __launch_bounds__(256) void k_convall(const float* __restrict__ Wq,
                                                 const float* __restrict__ Wk,
                                                 const float* __restrict__ Wv,
                                                 const float* __restrict__ Wo,
                                                 u16* __restrict__ dst) {
    const int NW = Hh * Cc * Cc;     // 262144
    int i = blockIdx.x * 256 + threadIdx.x;
    float v;
    if (i < NW) v = Wq[i];
    else if (i < 2 * NW) v = Wk[i - NW];
    else if (i < 3 * NW) v = Wv[i - 2 * NW];
    else if (i < 3 * NW + Cc * Cc) v = Wo[i - 3 * NW];
    else return;
    dst[i] = f2bf(v);
}

// One BK=32 step: 4x4 grid of 16x16x32 bf16 MFMAs per wave (wave covers 64x64).
__device__ __forceinline__ void mfma_step(const u16* As, const u16* Bs, int lane,
                                          int wm, int wn, floatx4 acc[4][4]) {
    const int r15 = lane & 15;
    const int kq  = (lane >> 4) << 3;
    shortx8 a[4], b[4];
#pragma unroll
    for (int i = 0; i < 4; ++i)
        a[i] = *(const shortx8*)(As + (wm * 64 + i * 16 + r15) * LST + kq);
#pragma unroll
    for (int j = 0; j < 4; ++j)
        b[j] = *(const shortx8*)(Bs + (wn * 64 + j * 16 + r15) * LST + kq);
#pragma unroll
    for (int i = 0; i < 4; ++i)
#pragma unroll
        for (int j = 0; j < 4; ++j)
            acc[i][j] = __builtin_amdgcn_mfma_f32_16x16x32_bf16(a[i], b[j], acc[i][j], 0, 0, 0);
}

// C[m,n] = sum_k A[m,k]*B[n,k], 128x128 tile, depth-2 prefetch (two reg sets, tile pairs).
__device__ __forceinline__ void gemm_bt_core(const u16* A, const u16* Bm, int lda, int ldb,
                                             int mbase, int mlast, int nbase, int nlast,
                                             int KD, u16* As, u16* Bs, floatx4 acc[4][4]) {
    int tid = threadIdx.x;
    int lane = tid & 63, wave = tid >> 6, wm = wave >> 1, wn = wave & 1;
    int row0 = tid >> 2, row1 = 64 + row0;
    int cole = (tid & 3) << 3;                 // 0,8,16,24
    int ga0 = mbase + row0; ga0 = ga0 <= mlast ? ga0 : mlast;
    int ga1 = mbase + row1; ga1 = ga1 <= mlast ? ga1 : mlast;
    int gb0 = nbase + row0; gb0 = gb0 <= nlast ? gb0 : nlast;
    int gb1 = nbase + row1; gb1 = gb1 <= nlast ? gb1 : nlast;
    const u16* pa0 = A  + (size_t)ga0 * lda + cole;
    const u16* pa1 = A  + (size_t)ga1 * lda + cole;
    const u16* pb0 = Bm + (size_t)gb0 * ldb + cole;
    const u16* pb1 = Bm + (size_t)gb1 * ldb + cole;
    shortx8 xa0 = *(const shortx8*)(pa0),      xa1 = *(const shortx8*)(pa1);
    shortx8 xb0 = *(const shortx8*)(pb0),      xb1 = *(const shortx8*)(pb1);
    shortx8 ya0 = *(const shortx8*)(pa0 + 32), ya1 = *(const shortx8*)(pa1 + 32);
    shortx8 yb0 = *(const shortx8*)(pb0 + 32), yb1 = *(const shortx8*)(pb1 + 32);
    for (int k0 = 0; k0 < KD; k0 += 64) {
        __syncthreads();
        *(shortx8*)(As + row0 * LST + cole) = xa0;
        *(shortx8*)(As + row1 * LST + cole) = xa1;
        *(shortx8*)(Bs + row0 * LST + cole) = xb0;
        *(shortx8*)(Bs + row1 * LST + cole) = xb1;
        int kp = k0 + 64;
        if (kp < KD) {
            xa0 = *(const shortx8*)(pa0 + kp); xa1 = *(const shortx8*)(pa1 + kp);
            xb0 = *(const shortx8*)(pb0 + kp); xb1 = *(const shortx8*)(pb1 + kp);
        }
        __syncthreads();
        mfma_step(As, Bs, lane, wm, wn, acc);
        if (k0 + 32 < KD) {
            __syncthreads();
            *(shortx8*)(As + row0 * LST + cole) = ya0;
            *(shortx8*)(As + row1 * LST + cole) = ya1;
            *(shortx8*)(Bs + row0 * LST + cole) = yb0;
            *(shortx8*)(Bs + row1 * LST + cole) = yb1;
            int kq2 = k0 + 96;
            if (kq2 < KD) {
                ya0 = *(const shortx8*)(pa0 + kq2); ya1 = *(const shortx8*)(pa1 + kq2);
                yb0 = *(const shortx8*)(pb0 + kq2); yb1 = *(const shortx8*)(pb1 + kq2);
            }
            __syncthreads();
            mfma_step(As, Bs, lane, wm, wn, acc);
        }
    }
}

// ---- K1: emb fp32 [B,T,C,N] -> x bf16 [B,S,C] ----
__global__ void k_transpose(const float* __restrict__ emb, u16* __restrict__ x) {
    __shared__ u16 tile[32][33];
    int bt = blockIdx.z;
    int c0 = blockIdx.y * 32, n0 = blockIdx.x * 32;
    const float* src = emb + (size_t)bt * Cc * NP;
#pragma unroll
    for (int rr = 0; rr < 32; rr += 8) {
        int c = c0 + threadIdx.y + rr;
        int n = n0 + threadIdx.x;
        u16 v = 0;
        if (n < NP) v = f2bf(src[(size_t)c * NP + n]);
        tile[threadIdx.y + rr][threadIdx.x] = v;
    }
    __syncthreads();
    int b = bt / Tt, t = bt % Tt;
    u16* dst = x + ((size_t)b * Ss + (size_t)t * NP) * Cc;
#pragma unroll
    for (int rr = 0; rr < 32; rr += 8) {
        int n = n0 + threadIdx.y + rr;
        int c = c0 + threadIdx.x;
        if (n < NP) dst[(size_t)n * Cc + c] = tile[threadIdx.x][threadIdx.y + rr];
    }
}

// ---- K2: QKV projections. V written transposed [C,S]. ----
__global__ __launch_bounds__(256) void k_qkv(const u16* __restrict__ x,
                                             const u16* __restrict__ Wall,
                                             u16* __restrict__ Q, u16* __restrict__ Kb,
                                             u16* __restrict__ Vt) {
    __shared__ __align__(16) u16 As[128 * LST], Bs[128 * LST];
    floatx4 acc[4][4];
#pragma unroll
    for (int i = 0; i < 4; ++i)
#pragma unroll
        for (int j = 0; j < 4; ++j) acc[i][j] = (floatx4)(0.f);
    int z = blockIdx.z;
    int qkv = z >> 4, bh = z & 15, b = bh >> 2, h = bh & 3;
    const u16* A = x + (size_t)b * Ss * Cc;
    const u16* W = Wall + (size_t)qkv * Hh * Cc * Cc + (size_t)h * Cc * Cc;
    int mbase = blockIdx.y * 128, nbase = blockIdx.x * 128;
    gemm_bt_core(A, W, Cc, Cc, mbase, Ss - 1, nbase, Cc - 1, Cc, As, Bs, acc);

    int tid = threadIdx.x, lane = tid & 63, wave = tid >> 6, wm = wave >> 1, wn = wave & 1;
    int rq = (lane >> 4) << 2, cn = lane & 15;
    if (qkv < 2) {
        u16* out = (qkv == 0 ? Q : Kb) + (size_t)bh * Ss * Cc;
#pragma unroll
        for (int i = 0; i < 4; ++i) {
            int mb = mbase + wm * 64 + i * 16 + rq;
#pragma unroll
            for (int j = 0; j < 4; ++j) {
                int n = nbase + wn * 64 + j * 16 + cn;
#pragma unroll
                for (int r = 0; r < 4; ++r) {
                    int m = mb + r;
                    if (m < Ss) out[(size_t)m * Cc + n] = f2bf(acc[i][j][r]);
                }
            }
        }
    } else {
        u16* out = Vt + (size_t)bh * Cc * Ss;
#pragma unroll
        for (int i = 0; i < 4; ++i) {
            int m0 = mbase + wm * 64 + i * 16 + rq;
            if (m0 < Ss) {
#pragma unroll
                for (int j = 0; j < 4; ++j) {
                    int n = nbase + wn * 64 + j * 16 + cn;
                    ushort4 v;
                    v.x = f2bf(acc[i][j][0]); v.y = f2bf(acc[i][j][1]);
                    v.z = f2bf(acc[i][j][2]); v.w = f2bf(acc[i][j][3]);
                    *(ushort4*)(out + (size_t)n * Ss + m0) = v;
                }
            }
        }
    }
}

// ---- K3: Sc = (Q K^T)*SCALE_S -> bf16, + fp32 sum/sumsq atomics per (b,h) ----
__global__ __launch_bounds__(256) void k_scores(const u16* __restrict__ Q,
                                                const u16* __restrict__ Kb,
                                                u16* __restrict__ Sc, float* __restrict__ stats) {
    __shared__ __align__(16) u16 As[128 * LST], Bs[128 * LST];
    __shared__ float sred[8];
    floatx4 acc[4][4];
#pragma unroll
    for (int i = 0; i < 4; ++i)
#pragma unroll
        for (int j = 0; j < 4; ++j) acc[i][j] = (floatx4)(0.f);
    int bh = blockIdx.z;
    const u16* A  = Q  + (size_t)bh * Ss * Cc;
    const u16* Bm = Kb + (size_t)bh * Ss * Cc;
    int mbase = blockIdx.y * 128, nbase = blockIdx.x * 128;
    gemm_bt_core(A, Bm, Cc, Cc, mbase, Ss - 1, nbase, Ss - 1, Cc, As, Bs, acc);

    int tid = threadIdx.x, lane = tid & 63, wave = tid >> 6, wm = wave >> 1, wn = wave & 1;
    int rq = (lane >> 4) << 2, cn = lane & 15;
    u16* out = Sc + (size_t)bh * Ss * Ss;
    float lsum = 0.f, lsq = 0.f;
#pragma unroll
    for (int i = 0; i < 4; ++i) {
        int mb = mbase + wm * 64 + i * 16 + rq;
#pragma unroll
        for (int j = 0; j < 4; ++j) {
            int n = nbase + wn * 64 + j * 16 + cn;
            bool nv = n < Ss;
#pragma unroll
            for (int r = 0; r < 4; ++r) {
                int m = mb + r;
                if (nv && m < Ss) {
                    float v = acc[i][j][r] * SCALE_S;
                    out[(size_t)m * Ss + n] = f2bf(v);
                    lsum += v; lsq += v * v;
                }
            }
        }
    }
#pragma unroll
    for (int mk = 1; mk <= 32; mk <<= 1) { lsum += __shfl_xor(lsum, mk); lsq += __shfl_xor(lsq, mk); }
    if (lane == 0) { sred[wave] = lsum; sred[4 + wave] = lsq; }
    __syncthreads();
    if (tid == 0) atomicAdd(&stats[bh * 4 + 0], sred[0] + sred[1] + sred[2] + sred[3]);
    if (tid == 1) atomicAdd(&stats[bh * 4 + 1], sred[4] + sred[5] + sred[6] + sred[7]);
}

// ---- K5: softmax(norm(Sc)) @ V. Block 32m x 256n (4 waves 1x4, wave 32x64).
// Full C-width per block: each Sc element loaded + exp'd EXACTLY ONCE.
// A staged as 8B chunks so all 256 threads share exp work (4 exps/thread/k-tile).
// Depth-2 prefetch; stats inline; head-mean fused (32 atomics/thread). ----
__global__ __launch_bounds__(256) void k_pv(const u16* __restrict__ Sc,
                                            const u16* __restrict__ Vt,
                                            const float* __restrict__ stats,
                                            float* __restrict__ ctxm) {
    __shared__ __align__(16) u16 As[32 * LST], Bs[256 * LST];   // 2KB + 16KB
    __shared__ float rs[32];
    floatx4 acc[2][4];
#pragma unroll
    for (int i = 0; i < 2; ++i)
#pragma unroll
        for (int j = 0; j < 4; ++j) acc[i][j] = (floatx4)(0.f);
    int bh = blockIdx.y;
    float inv  = 1.f / ((float)Ss * (float)Ss);
    float mean = stats[bh * 4] * inv;
    float var  = fmaxf(stats[bh * 4 + 1] * inv - mean * mean, 0.f);
    float istd = rsqrtf(var + 1e-5f);
    float aa = istd * 1.44269504f;   // log2(e)*istd
    float bb = -mean * aa;
    const u16* A  = Sc + (size_t)bh * Ss * Ss;   // [S][S]
    const u16* Bm = Vt + (size_t)bh * Cc * Ss;   // [C][S]
    int mbase = blockIdx.x * 32;      // 49 m-tiles, 49*32 = 1568 exact (no clamp)
    int tid = threadIdx.x, lane = tid & 63, wave = tid >> 6;
    // A staging: 8B chunks; row = tid>>3 (0..31), col = (tid&7)*4
    int rowA = tid >> 3;
    int colA = (tid & 7) << 2;
    const u16* pa = A + (size_t)(mbase + rowA) * Ss + colA;
    // B staging: 16B chunks, 4/thread; chunk c = tid + j*256: row=c>>2 (0..255), col=(c&3)*8
    const u16* pb[4];
    int rB[4], cB[4];
#pragma unroll
    for (int j = 0; j < 4; ++j) {
        int c = tid + j * 256;
        rB[j] = c >> 2; cB[j] = (c & 3) << 3;
        pb[j] = Bm + (size_t)rB[j] * Ss + cB[j];
    }
    float rsum = 0.f;

    auto ld4exp = [&](const u16* p) -> shortx4 {
        shortx4 v = *(const shortx4*)(p);
        shortx4 o;
#pragma unroll
        for (int e = 0; e < 4; ++e) {
            float ex = exp2f(bf2f((u16)v[e]) * aa + bb);
            rsum += ex; o[e] = (short)f2bf(ex);
        }
        return o;
    };

    const int r15 = lane & 15;
    const int kq  = (lane >> 4) << 3;

    shortx4 xa = ld4exp(pa), ya = ld4exp(pa + 32);
    shortx8 xb[4], yb[4];
#pragma unroll
    for (int j = 0; j < 4; ++j) {
        xb[j] = *(const shortx8*)(pb[j]);
        yb[j] = *(const shortx8*)(pb[j] + 32);
    }

    for (int k0 = 0; k0 < Ss; k0 += 64) {
        __syncthreads();
        *(shortx4*)(As + rowA * LST + colA) = xa;
#pragma unroll
        for (int j = 0; j < 4; ++j)
            *(shortx8*)(Bs + rB[j] * LST + cB[j]) = xb[j];
        int kp = k0 + 64;
        if (kp < Ss) {
            xa = ld4exp(pa + kp);
#pragma unroll
            for (int j = 0; j < 4; ++j) xb[j] = *(const shortx8*)(pb[j] + kp);
        }
        __syncthreads();
        {
            shortx8 a[2], b[4];
#pragma unroll
            for (int i = 0; i < 2; ++i)
                a[i] = *(const shortx8*)(As + (i * 16 + r15) * LST + kq);
#pragma unroll
            for (int j = 0; j < 4; ++j)
                b[j] = *(const shortx8*)(Bs + (wave * 64 + j * 16 + r15) * LST + kq);
#pragma unroll
            for (int i = 0; i < 2; ++i)
#pragma unroll
                for (int j = 0; j < 4; ++j)
                    acc[i][j] = __builtin_amdgcn_mfma_f32_16x16x32_bf16(a[i], b[j], acc[i][j], 0, 0, 0);
        }
        if (k0 + 32 < Ss) {
            __syncthreads();
            *(shortx4*)(As + rowA * LST + colA) = ya;
#pragma unroll
            for (int j = 0; j < 4; ++j)
                *(shortx8*)(Bs + rB[j] * LST + cB[j]) = yb[j];
            int kq2 = k0 + 96;
            if (kq2 < Ss) {
                ya = ld4exp(pa + kq2);
#pragma unroll
                for (int j = 0; j < 4; ++j) yb[j] = *(const shortx8*)(pb[j] + kq2);
            }
            __syncthreads();
            shortx8 a[2], b[4];
#pragma unroll
            for (int i = 0; i < 2; ++i)
                a[i] = *(const shortx8*)(As + (i * 16 + r15) * LST + kq);
#pragma unroll
            for (int j = 0; j < 4; ++j)
                b[j] = *(const shortx8*)(Bs + (wave * 64 + j * 16 + r15) * LST + kq);
#pragma unroll
            for (int i = 0; i < 2; ++i)
#pragma unroll
                for (int j = 0; j < 4; ++j)
                    acc[i][j] = __builtin_amdgcn_mfma_f32_16x16x32_bf16(a[i], b[j], acc[i][j], 0, 0, 0);
        }
    }
    // row rowA handled by 8 consecutive threads (same wave): xor-reduce over tid&7
    rsum += __shfl_xor(rsum, 1); rsum += __shfl_xor(rsum, 2); rsum += __shfl_xor(rsum, 4);
    __syncthreads();
    if ((tid & 7) == 0) rs[rowA] = rsum;
    __syncthreads();

    // fused head-mean: ctxm[b,m,n] += 0.25 * acc / rowsum[m]
    int b = bh >> 2;
    float* outp = ctxm + (size_t)b * Ss * Cc;
    int rq = (lane >> 4) << 2, cn = lane & 15;
#pragma unroll
    for (int i = 0; i < 2; ++i) {
        int ml = i * 16 + rq;
#pragma unroll
        for (int r = 0; r < 4; ++r) {
            int m = mbase + ml + r;      // always < Ss (exact tiling)
            float invs = 0.25f / rs[ml + r];
#pragma unroll
            for (int j = 0; j < 4; ++j) {
                int n = wave * 64 + j * 16 + cn;
                atomicAdd(&outp[(size_t)m * Cc + n], acc[i][j][r] * invs);
            }
        }
    }
}

// ---- K6: O = ctxm(fp32) @ Wo^T -> fp32 d_out (flat [B,S,C] == [B,T,C,N]) ----
__global__ __launch_bounds__(256) void k_out(const float* __restrict__ ctxm,
                                             const u16* __restrict__ Wo, float* __restrict__ out) {
    __shared__ __align__(16) u16 As[128 * LST], Bs[128 * LST];
    floatx4 acc[4][4];
#pragma unroll
    for (int i = 0; i < 4; ++i)
#pragma unroll
        for (int j = 0; j < 4; ++j) acc[i][j] = (floatx4)(0.f);
    int b = blockIdx.z;
    const float* A = ctxm + (size_t)b * Ss * Cc;
    int mbase = blockIdx.y * 128, nbase = blockIdx.x * 128;
    int tid = threadIdx.x, lane = tid & 63, wave = tid >> 6, wm = wave >> 1, wn = wave & 1;
    int row0 = tid >> 2, row1 = 64 + row0;
    int cole = (tid & 3) << 3;
    int ga0 = mbase + row0; ga0 = ga0 <= Ss - 1 ? ga0 : Ss - 1;
    int ga1 = mbase + row1; ga1 = ga1 <= Ss - 1 ? ga1 : Ss - 1;
    const float* pa0 = A + (size_t)ga0 * Cc + cole;
    const float* pa1 = A + (size_t)ga1 * Cc + cole;
    const u16* pb0 = Wo + (size_t)(nbase + row0 <= Cc - 1 ? nbase + row0 : Cc - 1) * Cc + cole;
    const u16* pb1 = Wo + (size_t)(nbase + row1 <= Cc - 1 ? nbase + row1 : Cc - 1) * Cc + cole;
    float4 a00 = *(const float4*)(pa0), a01 = *(const float4*)(pa0 + 4);
    float4 a10 = *(const float4*)(pa1), a11 = *(const float4*)(pa1 + 4);
    shortx8 vb0 = *(const shortx8*)(pb0);
    shortx8 vb1 = *(const shortx8*)(pb1);
    for (int k0 = 0; k0 < Cc; k0 += 32) {
        shortx8 o0, o1;
        o0[0] = (short)f2bf(a00.x); o0[1] = (short)f2bf(a00.y); o0[2] = (short)f2bf(a00.z); o0[3] = (short)f2bf(a00.w);
        o0[4] = (short)f2bf(a01.x); o0[5] = (short)f2bf(a01.y); o0[6] = (short)f2bf(a01.z); o0[7] = (short)f2bf(a01.w);
        o1[0] = (short)f2bf(a10.x); o1[1] = (short)f2bf(a10.y); o1[2] = (short)f2bf(a10.z); o1[3] = (short)f2bf(a10.w);
        o1[4] = (short)f2bf(a11.x); o1[5] = (short)f2bf(a11.y); o1[6] = (short)f2bf(a11.z); o1[7] = (short)f2bf(a11.w);
        __syncthreads();
        *(shortx8*)(As + row0 * LST + cole) = o0;
        *(shortx8*)(As + row1 * LST + cole) = o1;
        *(shortx8*)(Bs + row0 * LST + cole) = vb0;
        *(shortx8*)(Bs + row1 * LST + cole) = vb1;
        int k1 = k0 + 32;
        if (k1 < Cc) {
            a00 = *(const float4*)(pa0 + k1); a01 = *(const float4*)(pa0 + k1 + 4);
            a10 = *(const float4*)(pa1 + k1); a11 = *(const float4*)(pa1 + k1 + 4);
            vb0 = *(const shortx8*)(pb0 + k1);
            vb1 = *(const shortx8*)(pb1 + k1);
        }
        __syncthreads();
        mfma_step(As, Bs, lane, wm, wn, acc);
    }
    int rq = (lane >> 4) << 2, cn = lane & 15;
    float* o = out + (size_t)b * Ss * Cc;
#pragma unroll
    for (int i = 0; i < 4; ++i) {
        int mb = mbase + wm * 64 + i * 16 + rq;
#pragma unroll
        for (int j = 0; j < 4; ++j) {
            int n = nbase + wn * 64 + j * 16 + cn;
#pragma unroll
            for (int r = 0; r < 4; ++r) {
                int m = mb + r;
                if (m < Ss) o[(size_t)m * Cc + n] = acc[i][j][r];   // fp32 store
            }
        }
    }
}

extern "C" void kernel_launch(void* const* d_in, const int* in_sizes, int n_in,
                              void* d_out, int out_size, void* d_ws, size_t ws_size,
                              hipStream_t stream) {
    const float* emb = (const float*)d_in[0];
    float* out = (float*)d_out;

    char* ws = (char*)d_ws;
    size_t off = 0;
    auto alloc = [&](size_t bytes) -> void* {
        void* p = ws + off;
        off = (off + bytes + 255) & ~(size_t)255;
        return p;
    };
    // Total ~122.6 MiB. stats+ctxm adjacent -> single memset.
    float* stats = (float*)alloc(16 * 4 * sizeof(float));         // 256 B
    float* ctxm  = (float*)alloc((size_t)Bb * Ss * Cc * 4);       // 6.1 MiB fp32 head-mean accum
    u16* Wall = (u16*)alloc((size_t)(3 * Hh + 1) * Cc * Cc * 2);  // [Wq|Wk|Wv|Wo]
    u16* x    = (u16*)alloc((size_t)Bb * Ss * Cc * 2);            // 3.1 MiB
    u16* Q    = (u16*)alloc((size_t)Bb * Hh * Ss * Cc * 2);       // 12.25 MiB
    u16* Kb   = (u16*)alloc((size_t)Bb * Hh * Ss * Cc * 2);       // 12.25 MiB
    u16* Vt   = (u16*)alloc((size_t)Bb * Hh * Ss * Cc * 2);       // 12.25 MiB ([C,S])
    u16* Sc   = (u16*)alloc((size_t)Bb * Hh * Ss * Ss * 2);       // 75.0 MiB
    u16* Woc  = Wall + (size_t)3 * Hh * Cc * Cc;

    hipMemsetAsync(stats, 0, 256 + (size_t)Bb * Ss * Cc * 4, stream);

    k_convall<<<dim3(3328), dim3(256), 0, stream>>>((const float*)d_in[1], (const float*)d_in[2],
                                                    (const float*)d_in[3], (const float*)d_in[4], Wall);
    k_transpose<<<dim3(7, 8, 32), dim3(32, 8), 0, stream>>>(emb, x);
    k_qkv<<<dim3(2, 13, 48), dim3(256), 0, stream>>>(x, Wall, Q, Kb, Vt);
    k_scores<<<dim3(13, 13, 16), dim3(256), 0, stream>>>(Q, Kb, Sc, stats);
    k_pv<<<dim3(49, 16), dim3(256), 0, stream>>>(Sc, Vt, stats, ctxm);
    k_out<<<dim3(2, 13, 4), dim3(256), 0, stream>>>(ctxm, Woc, out);
}